// Round 5
// baseline (807.631 us; speedup 1.0000x reference)
//
#include <hip/hip_runtime.h>
#include <hip/hip_bf16.h>

#define B_ 8
#define C_ 64
#define H_ 128
#define W_ 128
#define CHW_ ((size_t)C_ * H_ * W_)
#define HW_  ((size_t)H_ * W_)

typedef unsigned short u16;
typedef unsigned int   u32;

__device__ __forceinline__ float bf2f(u16 h) {
    union { u32 u; float f; } c; c.u = ((u32)h) << 16; return c.f;
}
__device__ __forceinline__ u16 f2bf(float f) {
    union { float f; u32 u; } c; c.f = f;
    u32 u = c.u;
    u32 r = (u + 0x7fffu + ((u >> 16) & 1u)) >> 16;
    return (u16)r;
}
__device__ __forceinline__ u32 pack2(float a, float b) {
    return (u32)f2bf(a) | ((u32)f2bf(b) << 16);
}
__device__ __forceinline__ void unpack8(uint4 u, float* f) {
    f[0] = bf2f((u16)(u.x & 0xffff)); f[1] = bf2f((u16)(u.x >> 16));
    f[2] = bf2f((u16)(u.y & 0xffff)); f[3] = bf2f((u16)(u.y >> 16));
    f[4] = bf2f((u16)(u.z & 0xffff)); f[5] = bf2f((u16)(u.z >> 16));
    f[6] = bf2f((u16)(u.w & 0xffff)); f[7] = bf2f((u16)(u.w >> 16));
}
__device__ __forceinline__ uint4 pack8(const float* f) {
    uint4 u;
    u.x = pack2(f[0], f[1]); u.y = pack2(f[2], f[3]);
    u.z = pack2(f[4], f[5]); u.w = pack2(f[6], f[7]);
    return u;
}
__device__ __forceinline__ float sanit(float x, float lo, float hi) {
    return fminf(fmaxf(x, lo), hi);   // NaN-killing clamp
}

// ---------------------------------------------------------------------------
// Conv: q/k/v = conv3x3(x)+b (fp32 in, bf16 out). grid (H, 2, NB):
// y = co-half, z = batch. 256 thr = 32 co x 8 wgroups x 16 px.
// ---------------------------------------------------------------------------
__global__ __launch_bounds__(256) void conv_qkv_kernel(
    const float* __restrict__ x,
    const float* __restrict__ Wq, const float* __restrict__ bq,
    const float* __restrict__ Wk, const float* __restrict__ bk,
    const float* __restrict__ Wv, const float* __restrict__ bv,
    u16* __restrict__ q, u16* __restrict__ k, u16* __restrict__ v)
{
    const size_t boff = (size_t)blockIdx.z * CHW_;
    x += boff; q += boff; k += boff; v += boff;

    const int h   = blockIdx.x;
    const int tid = threadIdx.x;
    const int co  = blockIdx.y * 32 + (tid >> 3);
    const int w0  = (tid & 7) * 16;

    __shared__ float xs[32][3][128];   // 48 KiB

    float accq[16], acck[16], accv[16];
#pragma unroll
    for (int j = 0; j < 16; j++) { accq[j] = 0.f; acck[j] = 0.f; accv[j] = 0.f; }

    for (int chunk = 0; chunk < 2; chunk++) {
        const int ci0 = chunk * 32;
        __syncthreads();
#pragma unroll
        for (int t = 0; t < 12; t++) {
            int vid  = tid + t * 256;         // 0..3071 = 32ci*3dh*32w4
            int w4   = vid & 31;
            int rest = vid >> 5;              // 0..95
            int dh   = rest % 3;
            int ci   = rest / 3;
            int hh   = h - 1 + dh;
            float4 f = make_float4(0.f, 0.f, 0.f, 0.f);
            if (hh >= 0 && hh < H_)
                f = *(const float4*)(x + (size_t)((ci0 + ci) * H_ + hh) * W_ + w4 * 4);
            *(float4*)&xs[ci][dh][w4 * 4] = f;
        }
        __syncthreads();

        for (int ci = 0; ci < 32; ci++) {
            const int cig = ci0 + ci;
            const float* pq = Wq + (size_t)(co * C_ + cig) * 9;
            const float* pk = Wk + (size_t)(co * C_ + cig) * 9;
            const float* pv = Wv + (size_t)(co * C_ + cig) * 9;
            float wq9[9], wk9[9], wv9[9];
#pragma unroll
            for (int t = 0; t < 9; t++) {
                wq9[t] = pq[t]; wk9[t] = pk[t]; wv9[t] = pv[t];
            }
#pragma unroll
            for (int dh = 0; dh < 3; dh++) {
                const float* row = &xs[ci][dh][0];
                float xr[18];                  // x at w0-1 .. w0+16
#pragma unroll
                for (int jj = 0; jj < 4; jj++) {
                    float4 fv = *(const float4*)(row + w0 + jj * 4);
                    xr[1 + jj * 4 + 0] = fv.x; xr[1 + jj * 4 + 1] = fv.y;
                    xr[1 + jj * 4 + 2] = fv.z; xr[1 + jj * 4 + 3] = fv.w;
                }
                xr[0]  = (w0 > 0)        ? row[w0 - 1]  : 0.f;
                xr[17] = (w0 + 16 < W_)  ? row[w0 + 16] : 0.f;
#pragma unroll
                for (int dw = 0; dw < 3; dw++) {
                    const float wa = wq9[dh * 3 + dw];
                    const float wb = wk9[dh * 3 + dw];
                    const float wc = wv9[dh * 3 + dw];
#pragma unroll
                    for (int j = 0; j < 16; j++) {
                        const float xv = xr[j + dw];
                        accq[j] = fmaf(wa, xv, accq[j]);
                        acck[j] = fmaf(wb, xv, acck[j]);
                        accv[j] = fmaf(wc, xv, accv[j]);
                    }
                }
            }
        }
    }
    const float bq_ = bq[co], bk_ = bk[co], bv_ = bv[co];
    size_t off = (size_t)(co * H_ + h) * W_ + w0;
#pragma unroll
    for (int g = 0; g < 2; g++) {
        float fq[8], fk[8], fv[8];
#pragma unroll
        for (int r = 0; r < 8; r++) {
            fq[r] = accq[g * 8 + r] + bq_;
            fk[r] = acck[g * 8 + r] + bk_;
            fv[r] = accv[g * 8 + r] + bv_;
        }
        *(uint4*)(q + off + g * 8) = pack8(fq);
        *(uint4*)(k + off + g * 8) = pack8(fk);
        *(uint4*)(v + off + g * 8) = pack8(fv);
    }
}

// ---------------------------------------------------------------------------
// Column kernel: grid (W, 1, NB). eH[h,g] = sum_c q[c,h]k[c,g], diag masked.
// PHASE 0: (maxH,sumH). PHASE 1: attH -> out_H -> Ot[c][w][h] (bf16).
// ---------------------------------------------------------------------------
template <int PHASE>
__global__ __launch_bounds__(256) void col_kernel(
    const u16* __restrict__ q, const u16* __restrict__ k, const u16* __restrict__ v,
    float* __restrict__ maxH, float* __restrict__ sumH,
    const float* __restrict__ mFull, const float* __restrict__ denomA,
    u16* __restrict__ Ot)
{
    const size_t boff = (size_t)blockIdx.z * CHW_;
    const size_t soff = (size_t)blockIdx.z * HW_;
    q += boff; k += boff; v += boff; Ot += boff;
    maxH += soff; sumH += soff; mFull += soff; denomA += soff;

    const int w   = blockIdx.x;
    const int tid = threadIdx.x;
    const int ty  = tid >> 4, tx = tid & 15;
    const int h0  = ty * 8,   g0 = tx * 8;

    __shared__ float smem[12608];          // 50432 B
    float* Qs = smem;                      // [32][128]
    float* Ks = smem + 4096;               // [32][128]

    float S[8][8];
#pragma unroll
    for (int i = 0; i < 8; i++)
#pragma unroll
        for (int j = 0; j < 8; j++) S[i][j] = 0.f;

    for (int chunk = 0; chunk < 2; chunk++) {
        __syncthreads();
#pragma unroll
        for (int t = 0; t < 16; t++) {
            int idx = tid + t * 256;       // 0..4095
            int c = idx >> 7, hh = idx & 127;
            size_t off = (size_t)((chunk * 32 + c) * H_ + hh) * W_ + w;
            Qs[c * 128 + hh] = bf2f(q[off]);
            Ks[c * 128 + hh] = bf2f(k[off]);
        }
        __syncthreads();
        for (int c = 0; c < 32; c++) {
            float4 a0 = *(const float4*)&Qs[c * 128 + h0];
            float4 a1 = *(const float4*)&Qs[c * 128 + h0 + 4];
            float4 b0 = *(const float4*)&Ks[c * 128 + g0];
            float4 b1 = *(const float4*)&Ks[c * 128 + g0 + 4];
            float qa[8] = {a0.x, a0.y, a0.z, a0.w, a1.x, a1.y, a1.z, a1.w};
            float kb[8] = {b0.x, b0.y, b0.z, b0.w, b1.x, b1.y, b1.z, b1.w};
#pragma unroll
            for (int i = 0; i < 8; i++)
#pragma unroll
                for (int j = 0; j < 8; j++)
                    S[i][j] = fmaf(qa[i], kb[j], S[i][j]);
        }
    }
    if (ty == tx) {
#pragma unroll
        for (int i = 0; i < 8; i++) S[i][i] = -1e30f;
    }

    if constexpr (PHASE == 0) {
#pragma unroll
        for (int i = 0; i < 8; i++) {
            float m = S[i][0];
#pragma unroll
            for (int j = 1; j < 8; j++) m = fmaxf(m, S[i][j]);
            for (int o = 1; o < 16; o <<= 1) m = fmaxf(m, __shfl_xor(m, o));
            float s = 0.f;
#pragma unroll
            for (int j = 0; j < 8; j++) s += __expf(S[i][j] - m);
            for (int o = 1; o < 16; o <<= 1) s += __shfl_xor(s, o);
            if (tx == 0) {
                int pix = (h0 + i) * W_ + w;
                maxH[pix] = m; sumH[pix] = s;
            }
        }
    } else {
        float mr[8], rr[8];
#pragma unroll
        for (int i = 0; i < 8; i++) {
            int pix = (h0 + i) * W_ + w;
            mr[i] = sanit(mFull[pix], -3e38f, 3e38f);
            rr[i] = 1.0f / fmaxf(denomA[pix], 1e-30f);
        }
#pragma unroll
        for (int i = 0; i < 8; i++)
#pragma unroll
            for (int j = 0; j < 8; j++)
                S[i][j] = __expf(fminf(S[i][j] - mr[i], 0.f)) * rr[i];

        float (*PT)[132] = (float(*)[132])smem;     // [64][132]
        u16* Vs = (u16*)(smem + 8448);              // [64][130]

        __syncthreads();
#pragma unroll
        for (int t = 0; t < 32; t++) {
            int idx = tid + t * 256;
            int c = idx >> 7, g = idx & 127;
            Vs[c * 130 + g] = v[(size_t)(c * H_ + g) * W_ + w];
        }
        const int c0 = (tid & 15) * 4;
        const int hq = tid >> 4;
        float acc[4][8];
#pragma unroll
        for (int cc = 0; cc < 4; cc++)
#pragma unroll
            for (int i = 0; i < 8; i++) acc[cc][i] = 0.f;

        for (int half = 0; half < 2; half++) {
            __syncthreads();
            if ((tx >> 3) == half) {
#pragma unroll
                for (int j = 0; j < 8; j++)
#pragma unroll
                    for (int i = 0; i < 8; i++)
                        PT[(tx & 7) * 8 + j][ty * 8 + i] = S[i][j];
            }
            __syncthreads();
            for (int g2 = 0; g2 < 64; g2++) {
                float4 p0 = *(const float4*)&PT[g2][hq * 8];
                float4 p1 = *(const float4*)&PT[g2][hq * 8 + 4];
                float ph[8] = {p0.x, p0.y, p0.z, p0.w, p1.x, p1.y, p1.z, p1.w};
#pragma unroll
                for (int cc = 0; cc < 4; cc++) {
                    float vv = bf2f(Vs[(c0 + cc) * 130 + half * 64 + g2]);
#pragma unroll
                    for (int i = 0; i < 8; i++)
                        acc[cc][i] = fmaf(vv, ph[i], acc[cc][i]);
                }
            }
        }
#pragma unroll
        for (int cc = 0; cc < 4; cc++) {
            size_t off = (size_t)((c0 + cc) * W_ + w) * H_ + hq * 8;
            *(uint4*)(Ot + off) = pack8(acc[cc]);
        }
    }
}

// ---------------------------------------------------------------------------
// Row kernel: grid (H, 1, NB). eW[w,g] = sum_c q[c,w]k[c,g].
// PHASE 0: merge stats -> (mF, dn). PHASE 1: attW -> out_W; final combine,
// fp32 output store.
// ---------------------------------------------------------------------------
template <int PHASE>
__global__ __launch_bounds__(256) void row_kernel(
    const u16* __restrict__ q, const u16* __restrict__ k, const u16* __restrict__ v,
    const float* __restrict__ x, const float* __restrict__ gammap,
    const float* __restrict__ maxH, const float* __restrict__ sumH,
    float* __restrict__ mFull, float* __restrict__ denomA,
    const u16* __restrict__ Ot, float* __restrict__ out)
{
    const size_t boff = (size_t)blockIdx.z * CHW_;
    const size_t soff = (size_t)blockIdx.z * HW_;
    q += boff; k += boff; v += boff; Ot += boff; x += boff; out += boff;
    maxH += soff; sumH += soff; mFull += soff; denomA += soff;

    const int h   = blockIdx.x;
    const int tid = threadIdx.x;
    const int ty  = tid >> 4, tx = tid & 15;
    const int w0  = ty * 8,   g0 = tx * 8;

    __shared__ float smem[12608];
    float* Qs = smem;
    float* Ks = smem + 4096;

    float S[8][8];
#pragma unroll
    for (int i = 0; i < 8; i++)
#pragma unroll
        for (int j = 0; j < 8; j++) S[i][j] = 0.f;

    for (int chunk = 0; chunk < 2; chunk++) {
        __syncthreads();
#pragma unroll
        for (int t = 0; t < 2; t++) {
            int idx = tid + t * 256;       // 0..511 = 32c x 16w8
            int c = idx >> 4, w8 = idx & 15;
            size_t off = (size_t)((chunk * 32 + c) * H_ + h) * W_ + w8 * 8;
            float fq[8], fk[8];
            unpack8(*(const uint4*)(q + off), fq);
            unpack8(*(const uint4*)(k + off), fk);
            float* dq = &Qs[c * 128 + w8 * 8];
            float* dk = &Ks[c * 128 + w8 * 8];
#pragma unroll
            for (int r = 0; r < 8; r++) { dq[r] = fq[r]; dk[r] = fk[r]; }
        }
        __syncthreads();
        for (int c = 0; c < 32; c++) {
            float4 a0 = *(const float4*)&Qs[c * 128 + w0];
            float4 a1 = *(const float4*)&Qs[c * 128 + w0 + 4];
            float4 b0 = *(const float4*)&Ks[c * 128 + g0];
            float4 b1 = *(const float4*)&Ks[c * 128 + g0 + 4];
            float qa[8] = {a0.x, a0.y, a0.z, a0.w, a1.x, a1.y, a1.z, a1.w};
            float kb[8] = {b0.x, b0.y, b0.z, b0.w, b1.x, b1.y, b1.z, b1.w};
#pragma unroll
            for (int i = 0; i < 8; i++)
#pragma unroll
                for (int j = 0; j < 8; j++)
                    S[i][j] = fmaf(qa[i], kb[j], S[i][j]);
        }
    }

    if constexpr (PHASE == 0) {
#pragma unroll
        for (int i = 0; i < 8; i++) {
            float m = S[i][0];
#pragma unroll
            for (int j = 1; j < 8; j++) m = fmaxf(m, S[i][j]);
            for (int o = 1; o < 16; o <<= 1) m = fmaxf(m, __shfl_xor(m, o));
            float s = 0.f;
#pragma unroll
            for (int j = 0; j < 8; j++) s += __expf(S[i][j] - m);
            for (int o = 1; o < 16; o <<= 1) s += __shfl_xor(s, o);
            if (tx == 0) {
                int pix = h * W_ + (w0 + i);
                float mH = sanit(maxH[pix], -3e38f, 3e38f);
                float sH = sanit(sumH[pix], 0.f, 3e38f);
                float mm = fmaxf(mH, m);
                float dd = sH * __expf(fminf(mH - mm, 0.f)) + s * __expf(fminf(m - mm, 0.f));
                mFull[pix] = mm; denomA[pix] = dd;
            }
        }
    } else {
        float mr[8], rr[8];
#pragma unroll
        for (int i = 0; i < 8; i++) {
            int pix = h * W_ + (w0 + i);
            mr[i] = sanit(mFull[pix], -3e38f, 3e38f);
            rr[i] = 1.0f / fmaxf(denomA[pix], 1e-30f);
        }
#pragma unroll
        for (int i = 0; i < 8; i++)
#pragma unroll
            for (int j = 0; j < 8; j++)
                S[i][j] = __expf(fminf(S[i][j] - mr[i], 0.f)) * rr[i];

        float (*PT)[132] = (float(*)[132])smem;
        u16* Vs = (u16*)(smem + 8448);     // [64][130]

        __syncthreads();
#pragma unroll
        for (int t = 0; t < 4; t++) {
            int idx = tid + t * 256;       // 0..1023 = 64c x 16g8
            int c = idx >> 4, g8 = idx & 15;
            uint4 u = *(const uint4*)(v + (size_t)(c * H_ + h) * W_ + g8 * 8);
            u32* dst = (u32*)&Vs[c * 130 + g8 * 8];
            dst[0] = u.x; dst[1] = u.y; dst[2] = u.z; dst[3] = u.w;
        }
        const int c0  = (tid & 15) * 4;
        const int wq0 = (tid >> 4) * 8;
        float acc[4][8];
#pragma unroll
        for (int cc = 0; cc < 4; cc++)
#pragma unroll
            for (int i = 0; i < 8; i++) acc[cc][i] = 0.f;

        for (int half = 0; half < 2; half++) {
            __syncthreads();
            if ((tx >> 3) == half) {
#pragma unroll
                for (int j = 0; j < 8; j++)
#pragma unroll
                    for (int i = 0; i < 8; i++)
                        PT[(tx & 7) * 8 + j][ty * 8 + i] = S[i][j];
            }
            __syncthreads();
            for (int g2 = 0; g2 < 64; g2++) {
                float4 p0 = *(const float4*)&PT[g2][wq0];
                float4 p1 = *(const float4*)&PT[g2][wq0 + 4];
                float pw[8] = {p0.x, p0.y, p0.z, p0.w, p1.x, p1.y, p1.z, p1.w};
#pragma unroll
                for (int cc = 0; cc < 4; cc++) {
                    float vv = bf2f(Vs[(c0 + cc) * 130 + half * 64 + g2]);
#pragma unroll
                    for (int i = 0; i < 8; i++)
                        acc[cc][i] = fmaf(vv, pw[i], acc[cc][i]);
                }
            }
        }
        const float gmm = gammap[0];
#pragma unroll
        for (int cc = 0; cc < 4; cc++) {
            int c = c0 + cc;
            size_t xoff = (size_t)(c * H_ + h) * W_ + wq0;
            float4 x0 = *(const float4*)(x + xoff);
            float4 x1 = *(const float4*)(x + xoff + 4);
            float xv[8] = {x0.x, x0.y, x0.z, x0.w, x1.x, x1.y, x1.z, x1.w};
            float r8[8];
#pragma unroll
            for (int i = 0; i < 8; i++) {
                float ov = bf2f(Ot[(size_t)(c * W_ + wq0 + i) * H_ + h]);
                r8[i] = gmm * (acc[cc][i] + ov) + xv[i];
            }
            *(float4*)(out + xoff)     = make_float4(r8[0], r8[1], r8[2], r8[3]);
            *(float4*)(out + xoff + 4) = make_float4(r8[4], r8[5], r8[6], r8[7]);
        }
    }
}

// ---------------------------------------------------------------------------
// Inputs fp32, output fp32. Internals bf16 in ws.
// Parallel layout (ws >= 70 MB): q@0,k@16M,v@32M,Ot@48M (bf16, 16MB each),
//   stats@64M (4 x 512KB) = 66 MB. 5 launches, batch in grid.z.
// Serial fallback: per-batch 8.25 MB slices, 40 launches.
// ---------------------------------------------------------------------------
extern "C" void kernel_launch(void* const* d_in, const int* in_sizes, int n_in,
                              void* d_out, int out_size, void* d_ws, size_t ws_size,
                              hipStream_t stream)
{
    const float* x  = (const float*)d_in[0];
    const float* Wq = (const float*)d_in[1];
    const float* bq = (const float*)d_in[2];
    const float* Wk = (const float*)d_in[3];
    const float* bk = (const float*)d_in[4];
    const float* Wv = (const float*)d_in[5];
    const float* bv = (const float*)d_in[6];
    const float* gm = (const float*)d_in[7];
    float* out = (float*)d_out;

    char* ws = (char*)d_ws;
    dim3 blk(256);

    if (ws_size >= (size_t)70 * 1024 * 1024) {
        u16*   q    = (u16*)(ws + 0);
        u16*   k    = (u16*)(ws + (size_t)16 * 1024 * 1024);
        u16*   v    = (u16*)(ws + (size_t)32 * 1024 * 1024);
        u16*   Ot   = (u16*)(ws + (size_t)48 * 1024 * 1024);
        float* maxH = (float*)(ws + (size_t)64 * 1024 * 1024);
        float* sumH = (float*)(ws + (size_t)64 * 1024 * 1024 + 524288);
        float* mF   = (float*)(ws + (size_t)64 * 1024 * 1024 + 1048576);
        float* dn   = (float*)(ws + (size_t)64 * 1024 * 1024 + 1572864);

        conv_qkv_kernel<<<dim3(H_, 2, B_), blk, 0, stream>>>(x, Wq, bq, Wk, bk, Wv, bv, q, k, v);
        col_kernel<0><<<dim3(W_, 1, B_), blk, 0, stream>>>(q, k, v, maxH, sumH, mF, dn, Ot);
        row_kernel<0><<<dim3(H_, 1, B_), blk, 0, stream>>>(q, k, v, x, gm, maxH, sumH, mF, dn, Ot, out);
        col_kernel<1><<<dim3(W_, 1, B_), blk, 0, stream>>>(q, k, v, maxH, sumH, mF, dn, Ot);
        row_kernel<1><<<dim3(H_, 1, B_), blk, 0, stream>>>(q, k, v, x, gm, maxH, sumH, mF, dn, Ot, out);
    } else {
        u16*   q    = (u16*)(ws + 0);
        u16*   k    = (u16*)(ws + 2097152);
        u16*   v    = (u16*)(ws + 4194304);
        u16*   Ot   = (u16*)(ws + 6291456);
        float* maxH = (float*)(ws + 8388608);
        float* sumH = (float*)(ws + 8454144);
        float* mF   = (float*)(ws + 8519680);
        float* dn   = (float*)(ws + 8585216);

        for (int b = 0; b < B_; b++) {
            const float* xb = x + b * CHW_;
            float* ob = out + b * CHW_;
            conv_qkv_kernel<<<dim3(H_, 2, 1), blk, 0, stream>>>(xb, Wq, bq, Wk, bk, Wv, bv, q, k, v);
            col_kernel<0><<<dim3(W_, 1, 1), blk, 0, stream>>>(q, k, v, maxH, sumH, mF, dn, Ot);
            row_kernel<0><<<dim3(H_, 1, 1), blk, 0, stream>>>(q, k, v, xb, gm, maxH, sumH, mF, dn, Ot, ob);
            col_kernel<1><<<dim3(W_, 1, 1), blk, 0, stream>>>(q, k, v, maxH, sumH, mF, dn, Ot);
            row_kernel<1><<<dim3(H_, 1, 1), blk, 0, stream>>>(q, k, v, xb, gm, maxH, sumH, mF, dn, Ot, ob);
        }
    }
}

// Round 6
// 383.565 us; speedup vs baseline: 2.1056x; 2.1056x over previous
//
#include <hip/hip_runtime.h>
#include <hip/hip_bf16.h>

#define B_ 8
#define C_ 64
#define H_ 128
#define W_ 128
#define HW_  ((size_t)H_ * W_)          // 16384
#define CHW_ ((size_t)C_ * H_ * W_)     // 1048576

typedef unsigned short u16;
typedef unsigned int   u32;
typedef __attribute__((ext_vector_type(8))) short bf16x8;
typedef __attribute__((ext_vector_type(4))) float f32x4;

__device__ __forceinline__ float bf2f(u16 h) {
    union { u32 u; float f; } c; c.u = ((u32)h) << 16; return c.f;
}
__device__ __forceinline__ u16 f2bf(float f) {
    union { float f; u32 u; } c; c.f = f;
    u32 u = c.u;
    u32 r = (u + 0x7fffu + ((u >> 16) & 1u)) >> 16;
    return (u16)r;
}
__device__ __forceinline__ u32 pack2(float a, float b) {
    return (u32)f2bf(a) | ((u32)f2bf(b) << 16);
}
__device__ __forceinline__ void unpack8(uint4 u, float* f) {
    f[0] = bf2f((u16)(u.x & 0xffff)); f[1] = bf2f((u16)(u.x >> 16));
    f[2] = bf2f((u16)(u.y & 0xffff)); f[3] = bf2f((u16)(u.y >> 16));
    f[4] = bf2f((u16)(u.z & 0xffff)); f[5] = bf2f((u16)(u.z >> 16));
    f[6] = bf2f((u16)(u.w & 0xffff)); f[7] = bf2f((u16)(u.w >> 16));
}
__device__ __forceinline__ uint4 pack8(const float* f) {
    uint4 u;
    u.x = pack2(f[0], f[1]); u.y = pack2(f[2], f[3]);
    u.z = pack2(f[4], f[5]); u.w = pack2(f[6], f[7]);
    return u;
}
__device__ __forceinline__ float sanit(float x, float lo, float hi) {
    return fminf(fmaxf(x, lo), hi);   // NaN-killing clamp
}

// ---------------------------------------------------------------------------
// Weight prep: Wt[tap][cog(192)][ci(64)] bf16, cog = {q:0..63, k:64..127, v:128..191}
// ---------------------------------------------------------------------------
__global__ __launch_bounds__(256) void prep_weights(
    const float* __restrict__ Wq, const float* __restrict__ Wk,
    const float* __restrict__ Wv, u16* __restrict__ Wt)
{
    int tap = blockIdx.x;                               // 0..8
    int cog = blockIdx.y * 4 + (threadIdx.x >> 6);      // 0..191
    int ci  = threadIdx.x & 63;
    int arr = cog >> 6, co = cog & 63;
    const float* src = arr == 0 ? Wq : (arr == 1 ? Wk : Wv);
    Wt[tap * 12288 + cog * 64 + ci] = f2bf(src[(co * 64 + ci) * 9 + tap]);
}

// ---------------------------------------------------------------------------
// Conv via implicit-GEMM MFMA. grid (H, nb). 256 thr = 4 waves.
// Per block: C[192 co][128 px] = sum over 9 taps of Wt[tap] @ x_row(h+dh, +dw).
// Wave wv owns co rows [wv*48, wv*48+48): 3 M-tiles x 8 N-tiles of 16x16.
// A-frags: global (L2-hot Wt). B-frags: LDS xI[g=ch/8][130 px][8ch] bf16.
// ---------------------------------------------------------------------------
__global__ __launch_bounds__(256, 2) void conv_mfma_kernel(
    const float* __restrict__ x, const u16* __restrict__ Wt,
    const float* __restrict__ bq, const float* __restrict__ bk,
    const float* __restrict__ bv,
    u16* __restrict__ q, u16* __restrict__ k, u16* __restrict__ v)
{
    const int h    = blockIdx.x;
    const size_t boff = (size_t)blockIdx.y * CHW_;
    const int tid  = threadIdx.x;
    const int lane = tid & 63, wv = tid >> 6;
    const int ln15 = lane & 15, quad = lane >> 4;

    __shared__ u16 xI[8 * 1040];   // [g][pix 0..129][8ch], pix slot = w+1

    // zero the w-halo (pix 0 and 129) once
    if (tid < 64) {
        int p = (tid >= 32) ? 129 : 0;
        int j = tid & 31;
        *(u32*)(xI + ((j >> 2) * 1040 + p * 8 + (j & 3) * 2)) = 0u;
    }

    f32x4 acc[3][8];
#pragma unroll
    for (int mt = 0; mt < 3; mt++)
#pragma unroll
        for (int nt = 0; nt < 8; nt++)
            acc[mt][nt] = (f32x4){0.f, 0.f, 0.f, 0.f};

    for (int dh = 0; dh < 3; dh++) {
        int h2 = h - 1 + dh;
        if (h2 < 0 || h2 >= H_) continue;      // zero-pad row: skip (block-uniform)
        __syncthreads();
        {   // stage x[b, :, h2, :] -> xI (fp32 -> bf16, channel-interleaved)
            const int w4 = tid >> 3;           // 0..31
            const int cp = tid & 7;
            const float* xrow = x + boff + (size_t)h2 * W_;
#pragma unroll
            for (int it = 0; it < 4; it++) {
                int c = cp * 2 + it * 16;
                float4 f0 = *(const float4*)(xrow + (size_t)c * HW_ + w4 * 4);
                float4 f1 = *(const float4*)(xrow + (size_t)(c + 1) * HW_ + w4 * 4);
                float a0[4] = {f0.x, f0.y, f0.z, f0.w};
                float a1[4] = {f1.x, f1.y, f1.z, f1.w};
                int g = c >> 3, e = c & 7;
#pragma unroll
                for (int i = 0; i < 4; i++)
                    *(u32*)(xI + (g * 1040 + (w4 * 4 + i + 1) * 8 + e)) = pack2(a0[i], a1[i]);
            }
        }
        __syncthreads();
#pragma unroll
        for (int dw = 0; dw < 3; dw++) {
            const u16* wt = Wt + (dh * 3 + dw) * 12288;
#pragma unroll
            for (int ks = 0; ks < 2; ks++) {
                bf16x8 af[3], bfr[8];
#pragma unroll
                for (int mt = 0; mt < 3; mt++)
                    af[mt] = *(const bf16x8*)(wt + (wv * 48 + mt * 16 + ln15) * 64 + ks * 32 + quad * 8);
#pragma unroll
                for (int nt = 0; nt < 8; nt++)
                    bfr[nt] = *(const bf16x8*)(xI + ((quad + ks * 4) * 1040 + (nt * 16 + ln15 + dw) * 8));
#pragma unroll
                for (int mt = 0; mt < 3; mt++)
#pragma unroll
                    for (int nt = 0; nt < 8; nt++)
                        acc[mt][nt] = __builtin_amdgcn_mfma_f32_16x16x32_bf16(
                            af[mt], bfr[nt], acc[mt][nt], 0, 0, 0);
            }
        }
    }

    // epilogue: + bias, bf16, scatter to q/k/v[co][h][px]
#pragma unroll
    for (int mt = 0; mt < 3; mt++) {
        int base = wv * 48 + mt * 16;          // multiple of 16: tile never crosses arrays
        int arr  = base >> 6;
        u16* dst = (arr == 0 ? q : (arr == 1 ? k : v)) + boff;
        const float* bias = arr == 0 ? bq : (arr == 1 ? bk : bv);
        int coa = (base & 63) + quad * 4;
#pragma unroll
        for (int r = 0; r < 4; r++) {
            float bb = bias[coa + r];
            u16* drow = dst + (size_t)(coa + r) * HW_ + (size_t)h * W_;
#pragma unroll
            for (int nt = 0; nt < 8; nt++)
                drow[nt * 16 + ln15] = f2bf(acc[mt][nt][r] + bb);
        }
    }
}

// ---------------------------------------------------------------------------
// Transpose [c][h][w] -> [c][w][h] (bf16), 64x64 tiles via LDS.
// grid (4, C, nb*3): z -> (batch, array).
// ---------------------------------------------------------------------------
__global__ __launch_bounds__(256) void transpose_kernel(
    const u16* __restrict__ q, const u16* __restrict__ k, const u16* __restrict__ v,
    u16* __restrict__ qT, u16* __restrict__ kT, u16* __restrict__ vT)
{
    __shared__ u16 Ts[64 * 72];
    const int z  = blockIdx.z;
    const int lb = z / 3, arr = z % 3;
    const u16* src = (arr == 0 ? q : (arr == 1 ? k : v))
                     + (size_t)lb * CHW_ + (size_t)blockIdx.y * HW_;
    u16* dst = (arr == 0 ? qT : (arr == 1 ? kT : vT))
               + (size_t)lb * CHW_ + (size_t)blockIdx.y * HW_;
    const int ti = blockIdx.x & 1, tj = blockIdx.x >> 1;
    const int r0 = ti * 64, c0 = tj * 64;
    const int tid = threadIdx.x;
    const int r = tid >> 2, cq = tid & 3;
#pragma unroll
    for (int i = 0; i < 2; i++) {
        uint4 u = *(const uint4*)(src + (size_t)(r0 + r) * 128 + c0 + cq * 16 + i * 8);
        *(uint4*)(Ts + r * 72 + cq * 16 + i * 8) = u;
    }
    __syncthreads();
    const int wr = tid >> 2, hq = tid & 3;
    union { u16 o[16]; uint4 v4[2]; } t;
#pragma unroll
    for (int j = 0; j < 16; j++) t.o[j] = Ts[(hq * 16 + j) * 72 + wr];
    *(uint4*)(dst + (size_t)(c0 + wr) * 128 + r0 + hq * 16)     = t.v4[0];
    *(uint4*)(dst + (size_t)(c0 + wr) * 128 + r0 + hq * 16 + 8) = t.v4[1];
}

// ---------------------------------------------------------------------------
// Unified attention kernel. COL: pass (qT,kT,vT); block s = w, t-dim = h,
// diag-masked, phase0 writes (maxH,sumH), phase1 -> Ot[c][w][h] bf16.
// !COL: pass (q,k,v); block s = h, t-dim = w, phase0 merges stats -> (mF,dn),
// phase1 -> final fp32 out (gamma*(out_W + Ot) + x).
// ---------------------------------------------------------------------------
template <int PHASE, bool COL>
__global__ __launch_bounds__(256) void attn_kernel(
    const u16* __restrict__ qe, const u16* __restrict__ ke, const u16* __restrict__ ve,
    const float* __restrict__ x, const float* __restrict__ gammap,
    float* __restrict__ maxH, float* __restrict__ sumH,
    float* __restrict__ mFull, float* __restrict__ denomA,
    u16* __restrict__ Ot, float* __restrict__ out)
{
    const size_t boff = (size_t)blockIdx.z * CHW_;
    const size_t soff = (size_t)blockIdx.z * HW_;
    qe += boff; ke += boff; ve += boff; Ot += boff; x += boff; out += boff;
    maxH += soff; sumH += soff; mFull += soff; denomA += soff;

    const int s   = blockIdx.x;
    const int tid = threadIdx.x;
    const int ty  = tid >> 4, tx = tid & 15;
    const int t0  = ty * 8,   g0 = tx * 8;

    __shared__ float smem[12608];
    float* Qs = smem;                      // [32][128]
    float* Ks = smem + 4096;               // [32][128]

    float S[8][8];
#pragma unroll
    for (int i = 0; i < 8; i++)
#pragma unroll
        for (int j = 0; j < 8; j++) S[i][j] = 0.f;

    for (int chunk = 0; chunk < 2; chunk++) {
        __syncthreads();
#pragma unroll
        for (int t = 0; t < 2; t++) {
            int idx = tid + t * 256;       // 0..511 = 32c x 16 groups
            int c = idx >> 4, w8 = idx & 15;
            size_t off = ((size_t)(chunk * 32 + c) * 128 + s) * 128 + w8 * 8;
            float fq[8], fk[8];
            unpack8(*(const uint4*)(qe + off), fq);
            unpack8(*(const uint4*)(ke + off), fk);
            float* dq = &Qs[c * 128 + w8 * 8];
            float* dk = &Ks[c * 128 + w8 * 8];
#pragma unroll
            for (int r = 0; r < 8; r++) { dq[r] = fq[r]; dk[r] = fk[r]; }
        }
        __syncthreads();
        for (int c = 0; c < 32; c++) {
            float4 a0 = *(const float4*)&Qs[c * 128 + t0];
            float4 a1 = *(const float4*)&Qs[c * 128 + t0 + 4];
            float4 b0 = *(const float4*)&Ks[c * 128 + g0];
            float4 b1 = *(const float4*)&Ks[c * 128 + g0 + 4];
            float qa[8] = {a0.x, a0.y, a0.z, a0.w, a1.x, a1.y, a1.z, a1.w};
            float kb[8] = {b0.x, b0.y, b0.z, b0.w, b1.x, b1.y, b1.z, b1.w};
#pragma unroll
            for (int i = 0; i < 8; i++)
#pragma unroll
                for (int j = 0; j < 8; j++)
                    S[i][j] = fmaf(qa[i], kb[j], S[i][j]);
        }
    }
    if (COL && ty == tx) {
#pragma unroll
        for (int i = 0; i < 8; i++) S[i][i] = -1e30f;   // diag mask (h==g)
    }

    if constexpr (PHASE == 0) {
#pragma unroll
        for (int i = 0; i < 8; i++) {
            float m = S[i][0];
#pragma unroll
            for (int j = 1; j < 8; j++) m = fmaxf(m, S[i][j]);
            for (int o = 1; o < 16; o <<= 1) m = fmaxf(m, __shfl_xor(m, o));
            float ss = 0.f;
#pragma unroll
            for (int j = 0; j < 8; j++) ss += __expf(S[i][j] - m);
            for (int o = 1; o < 16; o <<= 1) ss += __shfl_xor(ss, o);
            if (tx == 0) {
                int pix = COL ? ((t0 + i) * W_ + s) : (s * W_ + (t0 + i));
                if (COL) {
                    maxH[pix] = m; sumH[pix] = ss;
                } else {
                    float mH = sanit(maxH[pix], -3e38f, 3e38f);
                    float sH = sanit(sumH[pix], 0.f, 3e38f);
                    float mm = fmaxf(mH, m);
                    float dd = sH * __expf(fminf(mH - mm, 0.f)) + ss * __expf(fminf(m - mm, 0.f));
                    mFull[pix] = mm; denomA[pix] = dd;
                }
            }
        }
    } else {
        float mr[8], rr[8];
#pragma unroll
        for (int i = 0; i < 8; i++) {
            int pix = COL ? ((t0 + i) * W_ + s) : (s * W_ + (t0 + i));
            mr[i] = sanit(mFull[pix], -3e38f, 3e38f);
            rr[i] = 1.0f / fmaxf(denomA[pix], 1e-30f);
        }
#pragma unroll
        for (int i = 0; i < 8; i++)
#pragma unroll
            for (int j = 0; j < 8; j++)
                S[i][j] = __expf(fminf(S[i][j] - mr[i], 0.f)) * rr[i];

        float (*PT)[132] = (float(*)[132])smem;
        u16* Vs = (u16*)(smem + 8448);     // [64][130]

        __syncthreads();
#pragma unroll
        for (int t = 0; t < 4; t++) {
            int idx = tid + t * 256;       // 0..1023 = 64c x 16 groups
            int c = idx >> 4, g8 = idx & 15;
            uint4 u = *(const uint4*)(ve + ((size_t)c * 128 + s) * 128 + g8 * 8);
            u32* dst = (u32*)&Vs[c * 130 + g8 * 8];
            dst[0] = u.x; dst[1] = u.y; dst[2] = u.z; dst[3] = u.w;
        }
        const int c0  = (tid & 15) * 4;
        const int tq0 = (tid >> 4) * 8;
        float acc[4][8];
#pragma unroll
        for (int cc = 0; cc < 4; cc++)
#pragma unroll
            for (int i = 0; i < 8; i++) acc[cc][i] = 0.f;

        for (int half = 0; half < 2; half++) {
            __syncthreads();
            if ((tx >> 3) == half) {
#pragma unroll
                for (int j = 0; j < 8; j++)
#pragma unroll
                    for (int i = 0; i < 8; i++)
                        PT[(tx & 7) * 8 + j][ty * 8 + i] = S[i][j];
            }
            __syncthreads();
            for (int g2 = 0; g2 < 64; g2++) {
                float4 p0 = *(const float4*)&PT[g2][tq0];
                float4 p1 = *(const float4*)&PT[g2][tq0 + 4];
                float pw[8] = {p0.x, p0.y, p0.z, p0.w, p1.x, p1.y, p1.z, p1.w};
#pragma unroll
                for (int cc = 0; cc < 4; cc++) {
                    float vv = bf2f(Vs[(c0 + cc) * 130 + half * 64 + g2]);
#pragma unroll
                    for (int i = 0; i < 8; i++)
                        acc[cc][i] = fmaf(vv, pw[i], acc[cc][i]);
                }
            }
        }
        if (COL) {
#pragma unroll
            for (int cc = 0; cc < 4; cc++) {
                size_t ooff = ((size_t)(c0 + cc) * 128 + s) * 128 + tq0;
                *(uint4*)(Ot + ooff) = pack8(acc[cc]);
            }
        } else {
            const float gmm = gammap[0];
#pragma unroll
            for (int cc = 0; cc < 4; cc++) {
                int c = c0 + cc;
                size_t xoff = ((size_t)c * 128 + s) * 128 + tq0;
                float4 x0 = *(const float4*)(x + xoff);
                float4 x1 = *(const float4*)(x + xoff + 4);
                float xv[8] = {x0.x, x0.y, x0.z, x0.w, x1.x, x1.y, x1.z, x1.w};
                float r8[8];
#pragma unroll
                for (int i = 0; i < 8; i++) {
                    float ov = bf2f(Ot[((size_t)c * 128 + tq0 + i) * 128 + s]);
                    r8[i] = gmm * (acc[cc][i] + ov) + xv[i];
                }
                *(float4*)(out + xoff)     = make_float4(r8[0], r8[1], r8[2], r8[3]);
                *(float4*)(out + xoff + 4) = make_float4(r8[4], r8[5], r8[6], r8[7]);
            }
        }
    }
}

// ---------------------------------------------------------------------------
// ws (per pass, nb batches): q|k|v|qT|kT|vT|Ot (bf16, nb*2MB each),
// stats 4 x nb*64KB, Wt 216KB. nb=8 needs ~114.2MB, nb=4 ~57.2MB.
// ---------------------------------------------------------------------------
extern "C" void kernel_launch(void* const* d_in, const int* in_sizes, int n_in,
                              void* d_out, int out_size, void* d_ws, size_t ws_size,
                              hipStream_t stream)
{
    const float* x  = (const float*)d_in[0];
    const float* Wq = (const float*)d_in[1];
    const float* bq = (const float*)d_in[2];
    const float* Wk = (const float*)d_in[3];
    const float* bk = (const float*)d_in[4];
    const float* Wv = (const float*)d_in[5];
    const float* bv = (const float*)d_in[6];
    const float* gm = (const float*)d_in[7];
    float* out = (float*)d_out;

    char* ws = (char*)d_ws;
    const size_t need1 = 7 * (size_t)B_ * CHW_ * 2 + 4 * (size_t)B_ * HW_ * 4 + 221184;
    int passes = (ws_size >= need1) ? 1 : 2;
    int nb = B_ / passes;

    const size_t SL = (size_t)nb * CHW_ * 2;
    const size_t ST = (size_t)nb * HW_ * 4;
    u16*   q    = (u16*)(ws);
    u16*   k    = (u16*)(ws + SL);
    u16*   v    = (u16*)(ws + 2 * SL);
    u16*   qT   = (u16*)(ws + 3 * SL);
    u16*   kT   = (u16*)(ws + 4 * SL);
    u16*   vT   = (u16*)(ws + 5 * SL);
    u16*   Ot   = (u16*)(ws + 6 * SL);
    float* maxH = (float*)(ws + 7 * SL);
    float* sumH = (float*)(ws + 7 * SL + ST);
    float* mF   = (float*)(ws + 7 * SL + 2 * ST);
    float* dn   = (float*)(ws + 7 * SL + 3 * ST);
    u16*   Wt   = (u16*)(ws + 7 * SL + 4 * ST);

    dim3 blk(256);
    prep_weights<<<dim3(9, 48), blk, 0, stream>>>(Wq, Wk, Wv, Wt);

    for (int p = 0; p < passes; p++) {
        const float* xb = x + (size_t)p * nb * CHW_;
        float* ob = out + (size_t)p * nb * CHW_;
        conv_mfma_kernel<<<dim3(H_, nb), blk, 0, stream>>>(xb, Wt, bq, bk, bv, q, k, v);
        transpose_kernel<<<dim3(4, C_, nb * 3), blk, 0, stream>>>(q, k, v, qT, kT, vT);
        attn_kernel<0, true ><<<dim3(W_, 1, nb), blk, 0, stream>>>(qT, kT, vT, xb, gm, maxH, sumH, mF, dn, Ot, ob);
        attn_kernel<0, false><<<dim3(H_, 1, nb), blk, 0, stream>>>(q,  k,  v,  xb, gm, maxH, sumH, mF, dn, Ot, ob);
        attn_kernel<1, true ><<<dim3(W_, 1, nb), blk, 0, stream>>>(qT, kT, vT, xb, gm, maxH, sumH, mF, dn, Ot, ob);
        attn_kernel<1, false><<<dim3(H_, 1, nb), blk, 0, stream>>>(q,  k,  v,  xb, gm, maxH, sumH, mF, dn, Ot, ob);
    }
}

// Round 7
// 240.643 us; speedup vs baseline: 3.3561x; 1.5939x over previous
//
#include <hip/hip_runtime.h>
#include <hip/hip_bf16.h>

#define B_ 8
#define C_ 64
#define H_ 128
#define W_ 128
#define HW_  ((size_t)H_ * W_)          // 16384
#define CHW_ ((size_t)C_ * H_ * W_)     // 1048576

typedef unsigned short u16;
typedef unsigned int   u32;
typedef __attribute__((ext_vector_type(8))) short bf16x8;
typedef __attribute__((ext_vector_type(4))) float f32x4;

__device__ __forceinline__ float bf2f(u16 h) {
    union { u32 u; float f; } c; c.u = ((u32)h) << 16; return c.f;
}
__device__ __forceinline__ u16 f2bf(float f) {
    union { float f; u32 u; } c; c.f = f;
    u32 u = c.u;
    u32 r = (u + 0x7fffu + ((u >> 16) & 1u)) >> 16;
    return (u16)r;
}
__device__ __forceinline__ u32 pack2(float a, float b) {
    return (u32)f2bf(a) | ((u32)f2bf(b) << 16);
}
__device__ __forceinline__ float sanit(float x, float lo, float hi) {
    return fminf(fmaxf(x, lo), hi);   // NaN-killing clamp
}

// ---------------------------------------------------------------------------
// Weight prep: Wt[tap][cog(192)][ci(64)] bf16, cog = {q:0..63, k:64..127, v:128..191}
// ---------------------------------------------------------------------------
__global__ __launch_bounds__(256) void prep_weights(
    const float* __restrict__ Wq, const float* __restrict__ Wk,
    const float* __restrict__ Wv, u16* __restrict__ Wt)
{
    int tap = blockIdx.x;                               // 0..8
    int cog = blockIdx.y * 4 + (threadIdx.x >> 6);      // 0..191
    int ci  = threadIdx.x & 63;
    int arr = cog >> 6, co = cog & 63;
    const float* src = arr == 0 ? Wq : (arr == 1 ? Wk : Wv);
    Wt[tap * 12288 + cog * 64 + ci] = f2bf(src[(co * 64 + ci) * 9 + tap]);
}

// ---------------------------------------------------------------------------
// Conv via implicit-GEMM MFMA (unchanged from round 6). grid (H, nb).
// ---------------------------------------------------------------------------
__global__ __launch_bounds__(256, 2) void conv_mfma_kernel(
    const float* __restrict__ x, const u16* __restrict__ Wt,
    const float* __restrict__ bq, const float* __restrict__ bk,
    const float* __restrict__ bv,
    u16* __restrict__ q, u16* __restrict__ k, u16* __restrict__ v)
{
    const int h    = blockIdx.x;
    const size_t boff = (size_t)blockIdx.y * CHW_;
    const int tid  = threadIdx.x;
    const int lane = tid & 63, wv = tid >> 6;
    const int ln15 = lane & 15, quad = lane >> 4;

    __shared__ u16 xI[8 * 1040];   // [g][pix 0..129][8ch], pix slot = w+1

    if (tid < 64) {
        int p = (tid >= 32) ? 129 : 0;
        int j = tid & 31;
        *(u32*)(xI + ((j >> 2) * 1040 + p * 8 + (j & 3) * 2)) = 0u;
    }

    f32x4 acc[3][8];
#pragma unroll
    for (int mt = 0; mt < 3; mt++)
#pragma unroll
        for (int nt = 0; nt < 8; nt++)
            acc[mt][nt] = (f32x4){0.f, 0.f, 0.f, 0.f};

    for (int dh = 0; dh < 3; dh++) {
        int h2 = h - 1 + dh;
        if (h2 < 0 || h2 >= H_) continue;
        __syncthreads();
        {
            const int w4 = tid >> 3;
            const int cp = tid & 7;
            const float* xrow = x + boff + (size_t)h2 * W_;
#pragma unroll
            for (int it = 0; it < 4; it++) {
                int c = cp * 2 + it * 16;
                float4 f0 = *(const float4*)(xrow + (size_t)c * HW_ + w4 * 4);
                float4 f1 = *(const float4*)(xrow + (size_t)(c + 1) * HW_ + w4 * 4);
                float a0[4] = {f0.x, f0.y, f0.z, f0.w};
                float a1[4] = {f1.x, f1.y, f1.z, f1.w};
                int g = c >> 3, e = c & 7;
#pragma unroll
                for (int i = 0; i < 4; i++)
                    *(u32*)(xI + (g * 1040 + (w4 * 4 + i + 1) * 8 + e)) = pack2(a0[i], a1[i]);
            }
        }
        __syncthreads();
#pragma unroll
        for (int dw = 0; dw < 3; dw++) {
            const u16* wt = Wt + (dh * 3 + dw) * 12288;
#pragma unroll
            for (int ks = 0; ks < 2; ks++) {
                bf16x8 af[3], bfr[8];
#pragma unroll
                for (int mt = 0; mt < 3; mt++)
                    af[mt] = *(const bf16x8*)(wt + (wv * 48 + mt * 16 + ln15) * 64 + ks * 32 + quad * 8);
#pragma unroll
                for (int nt = 0; nt < 8; nt++)
                    bfr[nt] = *(const bf16x8*)(xI + ((quad + ks * 4) * 1040 + (nt * 16 + ln15 + dw) * 8));
#pragma unroll
                for (int mt = 0; mt < 3; mt++)
#pragma unroll
                    for (int nt = 0; nt < 8; nt++)
                        acc[mt][nt] = __builtin_amdgcn_mfma_f32_16x16x32_bf16(
                            af[mt], bfr[nt], acc[mt][nt], 0, 0, 0);
            }
        }
    }

#pragma unroll
    for (int mt = 0; mt < 3; mt++) {
        int base = wv * 48 + mt * 16;
        int arr  = base >> 6;
        u16* dst = (arr == 0 ? q : (arr == 1 ? k : v)) + boff;
        const float* bias = arr == 0 ? bq : (arr == 1 ? bk : bv);
        int coa = (base & 63) + quad * 4;
#pragma unroll
        for (int r = 0; r < 4; r++) {
            float bb = bias[coa + r];
            u16* drow = dst + (size_t)(coa + r) * HW_ + (size_t)h * W_;
#pragma unroll
            for (int nt = 0; nt < 8; nt++)
                drow[nt * 16 + ln15] = f2bf(acc[mt][nt][r] + bb);
        }
    }
}

// ---------------------------------------------------------------------------
// NHWC transpose: [c][h][w] -> [pix][c]. One block per 64-pixel tile.
// grid (256, 2 arrays, nb).
// ---------------------------------------------------------------------------
__global__ __launch_bounds__(256) void nhwc_kernel(
    const u16* __restrict__ q, const u16* __restrict__ k,
    u16* __restrict__ qN, u16* __restrict__ kN)
{
    __shared__ u16 T[64 * 72];
    const u16* src = (blockIdx.y ? k : q) + (size_t)blockIdx.z * CHW_;
    u16* dst = (blockIdx.y ? kN : qN) + (size_t)blockIdx.z * CHW_;
    const int p0 = blockIdx.x * 64;
    const int tid = threadIdx.x;
    {
        int c = tid >> 2, j = (tid & 3) * 16;
        *(uint4*)(T + c * 72 + j)     = *(const uint4*)(src + (size_t)c * HW_ + p0 + j);
        *(uint4*)(T + c * 72 + j + 8) = *(const uint4*)(src + (size_t)c * HW_ + p0 + j + 8);
    }
    __syncthreads();
    {
        int p = tid >> 2, c0 = (tid & 3) * 16;
        union { u16 o[16]; uint4 v4[2]; } t;
#pragma unroll
        for (int i = 0; i < 16; i++) t.o[i] = T[(c0 + i) * 72 + p];
        *(uint4*)(dst + (size_t)(p0 + p) * 64 + c0)     = t.v4[0];
        *(uint4*)(dst + (size_t)(p0 + p) * 64 + c0 + 8) = t.v4[1];
    }
}

// ---------------------------------------------------------------------------
// vT: [c][h][w] -> [c][w][h] (64x64 tiles). grid (4, C, nb).
// ---------------------------------------------------------------------------
__global__ __launch_bounds__(256) void vt_kernel(
    const u16* __restrict__ v, u16* __restrict__ vT)
{
    __shared__ u16 Ts[64 * 72];
    const u16* src = v  + (size_t)blockIdx.z * CHW_ + (size_t)blockIdx.y * HW_;
    u16* dst       = vT + (size_t)blockIdx.z * CHW_ + (size_t)blockIdx.y * HW_;
    const int ti = blockIdx.x & 1, tj = blockIdx.x >> 1;
    const int r0 = ti * 64, c0 = tj * 64;
    const int tid = threadIdx.x;
    const int r = tid >> 2, cq = tid & 3;
#pragma unroll
    for (int i = 0; i < 2; i++) {
        uint4 u = *(const uint4*)(src + (size_t)(r0 + r) * 128 + c0 + cq * 16 + i * 8);
        *(uint4*)(Ts + r * 72 + cq * 16 + i * 8) = u;
    }
    __syncthreads();
    const int wr = tid >> 2, hq = tid & 3;
    union { u16 o[16]; uint4 v4[2]; } t;
#pragma unroll
    for (int j = 0; j < 16; j++) t.o[j] = Ts[(hq * 16 + j) * 72 + wr];
    *(uint4*)(dst + (size_t)(c0 + wr) * 128 + r0 + hq * 16)     = t.v4[0];
    *(uint4*)(dst + (size_t)(c0 + wr) * 128 + r0 + hq * 16 + 8) = t.v4[1];
}

// ---------------------------------------------------------------------------
// MFMA attention. Block = (s, b), 4 waves; wave wv owns t-rows [wv*32,+32).
// COL: s=w, t=h, g=h', diag mask, ve=vT [c][w][h].  ROW: s=h, t=w, g=w', ve=v.
// S = Q K^T (K=64, 8x8 N-tiles x 2 K-steps); PHASE0 -> stats;
// PHASE1 -> P (bf16, LDS) -> PV (K=128) -> OtN (COL) / final out (ROW).
// ---------------------------------------------------------------------------
template <int PHASE, bool COL>
__global__ __launch_bounds__(256, 3) void attn_kernel(
    const u16* __restrict__ qN, const u16* __restrict__ kN,
    const u16* __restrict__ ve,
    const float* __restrict__ x, const float* __restrict__ gammap,
    float* __restrict__ maxH, float* __restrict__ sumH,
    float* __restrict__ mFull, float* __restrict__ denomA,
    u16* __restrict__ OtN, float* __restrict__ out)
{
    const size_t boff = (size_t)blockIdx.z * CHW_;
    const size_t soff = (size_t)blockIdx.z * HW_;
    qN += boff; kN += boff; ve += boff; OtN += boff; x += boff; out += boff;
    maxH += soff; sumH += soff; mFull += soff; denomA += soff;

    const int s    = blockIdx.x;
    const int tid  = threadIdx.x;
    const int lane = tid & 63, wv = tid >> 6;
    const int ln15 = lane & 15, quad = lane >> 4;

    __shared__ __align__(16) u16 smemU[18432];   // 36864 B multi-purpose
    u16* Qs = smemU;                             // [128 t][72]
    u16* Ks = smemU + 9216;                      // [128 g][72]

    // ---- stage Q,K slabs as [t][c] ----
#pragma unroll
    for (int it = 0; it < 4; it++) {
        int idx = tid + it * 256;                // 0..1023
        int t = idx >> 3, cg = (idx & 7) * 8;
        size_t off = COL ? ((size_t)t * 8192 + (size_t)s * 64 + cg)
                         : ((size_t)s * 8192 + (size_t)t * 64 + cg);
        *(uint4*)(Qs + t * 72 + cg) = *(const uint4*)(qN + off);
        *(uint4*)(Ks + t * 72 + cg) = *(const uint4*)(kN + off);
    }
    __syncthreads();

    // ---- S = Q K^T ----
    f32x4 Sc[2][8];
#pragma unroll
    for (int mt = 0; mt < 2; mt++)
#pragma unroll
        for (int nt = 0; nt < 8; nt++)
            Sc[mt][nt] = (f32x4){0.f, 0.f, 0.f, 0.f};

#pragma unroll
    for (int ks = 0; ks < 2; ks++) {
        bf16x8 aq[2];
#pragma unroll
        for (int mt = 0; mt < 2; mt++)
            aq[mt] = *(const bf16x8*)(Qs + (wv * 32 + mt * 16 + ln15) * 72 + ks * 32 + quad * 8);
#pragma unroll
        for (int nt = 0; nt < 8; nt++) {
            bf16x8 bk_ = *(const bf16x8*)(Ks + (nt * 16 + ln15) * 72 + ks * 32 + quad * 8);
#pragma unroll
            for (int mt = 0; mt < 2; mt++)
                Sc[mt][nt] = __builtin_amdgcn_mfma_f32_16x16x32_bf16(aq[mt], bk_, Sc[mt][nt], 0, 0, 0);
        }
    }

    if (COL) {   // diag mask t==g
#pragma unroll
        for (int mt = 0; mt < 2; mt++)
#pragma unroll
            for (int nt = 0; nt < 8; nt++)
#pragma unroll
                for (int r = 0; r < 4; r++) {
                    int tt = wv * 32 + mt * 16 + quad * 4 + r;
                    if (tt == nt * 16 + ln15) Sc[mt][nt][r] = -1e30f;
                }
    }

    if constexpr (PHASE == 0) {
#pragma unroll
        for (int mt = 0; mt < 2; mt++)
#pragma unroll
            for (int r = 0; r < 4; r++) {
                float m = Sc[mt][0][r];
#pragma unroll
                for (int nt = 1; nt < 8; nt++) m = fmaxf(m, Sc[mt][nt][r]);
                for (int o = 1; o < 16; o <<= 1) m = fmaxf(m, __shfl_xor(m, o));
                float ss = 0.f;
#pragma unroll
                for (int nt = 0; nt < 8; nt++) ss += __expf(Sc[mt][nt][r] - m);
                for (int o = 1; o < 16; o <<= 1) ss += __shfl_xor(ss, o);
                if (ln15 == 0) {
                    int tt  = wv * 32 + mt * 16 + quad * 4 + r;
                    int pix = COL ? tt * W_ + s : s * W_ + tt;
                    if (COL) {
                        maxH[pix] = m; sumH[pix] = ss;
                    } else {
                        float mH = sanit(maxH[pix], -3e38f, 3e38f);
                        float sH = sanit(sumH[pix], 0.f, 3e38f);
                        float mm = fmaxf(mH, m);
                        float dd = sH * __expf(fminf(mH - mm, 0.f)) + ss * __expf(fminf(m - mm, 0.f));
                        mFull[pix] = mm; denomA[pix] = dd;
                    }
                }
            }
        return;
    } else {
        // per-row global stats
        float mr[2][4], rr[2][4];
#pragma unroll
        for (int mt = 0; mt < 2; mt++)
#pragma unroll
            for (int r = 0; r < 4; r++) {
                int tt  = wv * 32 + mt * 16 + quad * 4 + r;
                int pix = COL ? tt * W_ + s : s * W_ + tt;
                mr[mt][r] = sanit(mFull[pix], -3e38f, 3e38f);
                rr[mt][r] = 1.0f / fmaxf(denomA[pix], 1e-30f);
            }
        __syncthreads();                 // all waves done with Qs/Ks
        u16* Ps = smemU;                 // [128 t][136]
#pragma unroll
        for (int mt = 0; mt < 2; mt++)
#pragma unroll
            for (int nt = 0; nt < 8; nt++)
#pragma unroll
                for (int r = 0; r < 4; r++) {
                    float p = __expf(fminf(Sc[mt][nt][r] - mr[mt][r], 0.f)) * rr[mt][r];
                    Ps[(wv * 32 + mt * 16 + quad * 4 + r) * 136 + nt * 16 + ln15] = f2bf(p);
                }
        __syncthreads();

        // ---- PV: out[t][c] = sum_g P[t][g] * V[c][g] ----
        f32x4 Oc[2][4];
#pragma unroll
        for (int mt = 0; mt < 2; mt++)
#pragma unroll
            for (int nt = 0; nt < 4; nt++)
                Oc[mt][nt] = (f32x4){0.f, 0.f, 0.f, 0.f};

#pragma unroll
        for (int kg = 0; kg < 4; kg++) {
            bf16x8 ap[2];
#pragma unroll
            for (int mt = 0; mt < 2; mt++)
                ap[mt] = *(const bf16x8*)(Ps + (wv * 32 + mt * 16 + ln15) * 136 + kg * 32 + quad * 8);
#pragma unroll
            for (int nt = 0; nt < 4; nt++) {
                bf16x8 bv_ = *(const bf16x8*)(ve + (size_t)(nt * 16 + ln15) * HW_ + (size_t)s * 128 + kg * 32 + quad * 8);
#pragma unroll
                for (int mt = 0; mt < 2; mt++)
                    Oc[mt][nt] = __builtin_amdgcn_mfma_f32_16x16x32_bf16(ap[mt], bv_, Oc[mt][nt], 0, 0, 0);
            }
        }
        __syncthreads();

        if (COL) {
            u16* Ob = smemU;             // [128 t][72]
#pragma unroll
            for (int mt = 0; mt < 2; mt++)
#pragma unroll
                for (int nt = 0; nt < 4; nt++)
#pragma unroll
                    for (int r = 0; r < 4; r++)
                        Ob[(wv * 32 + mt * 16 + quad * 4 + r) * 72 + nt * 16 + ln15] = f2bf(Oc[mt][nt][r]);
            __syncthreads();
#pragma unroll
            for (int it = 0; it < 4; it++) {
                int idx = tid + it * 256;
                int t = idx >> 3, cg = (idx & 7) * 8;
                *(uint4*)(OtN + (size_t)t * 8192 + (size_t)s * 64 + cg) = *(uint4*)(Ob + t * 72 + cg);
            }
        } else {
            float* Of = (float*)smemU;   // [64 c][132 w] f32
            const float gmm = gammap[0];
#pragma unroll
            for (int mt = 0; mt < 2; mt++)
#pragma unroll
                for (int nt = 0; nt < 4; nt++) {
                    float fv[4];
#pragma unroll
                    for (int r = 0; r < 4; r++) {
                        int tt = wv * 32 + mt * 16 + quad * 4 + r;
                        u16 ot = OtN[(size_t)s * 8192 + (size_t)tt * 64 + nt * 16 + ln15];
                        fv[r] = gmm * (Oc[mt][nt][r] + bf2f(ot));
                    }
                    int c  = nt * 16 + ln15;
                    int w0 = wv * 32 + mt * 16 + quad * 4;
                    *(float4*)(Of + c * 132 + w0) = make_float4(fv[0], fv[1], fv[2], fv[3]);
                }
            __syncthreads();
            int c = tid >> 2, w0 = (tid & 3) * 32;
#pragma unroll
            for (int i = 0; i < 8; i++) {
                int w = w0 + i * 4;
                float4 xo = *(const float4*)(x + (size_t)c * HW_ + (size_t)s * 128 + w);
                float4 of = *(const float4*)(Of + c * 132 + w);
                *(float4*)(out + (size_t)c * HW_ + (size_t)s * 128 + w) =
                    make_float4(of.x + xo.x, of.y + xo.y, of.z + xo.z, of.w + xo.w);
            }
        }
    }
}

// ---------------------------------------------------------------------------
// ws: q|k|v|qN|kN|vT|OtN (bf16, nb*2MB each) + stats 4 x nb*64KB + Wt 216KB.
// nb=8 ~114.2MB (proven), fallback 2-pass nb=4.
// ---------------------------------------------------------------------------
extern "C" void kernel_launch(void* const* d_in, const int* in_sizes, int n_in,
                              void* d_out, int out_size, void* d_ws, size_t ws_size,
                              hipStream_t stream)
{
    const float* x  = (const float*)d_in[0];
    const float* Wq = (const float*)d_in[1];
    const float* bq = (const float*)d_in[2];
    const float* Wk = (const float*)d_in[3];
    const float* bk = (const float*)d_in[4];
    const float* Wv = (const float*)d_in[5];
    const float* bv = (const float*)d_in[6];
    const float* gm = (const float*)d_in[7];
    float* out = (float*)d_out;

    char* ws = (char*)d_ws;
    const size_t need1 = 7 * (size_t)B_ * CHW_ * 2 + 4 * (size_t)B_ * HW_ * 4 + 221184;
    int passes = (ws_size >= need1) ? 1 : 2;
    int nb = B_ / passes;

    const size_t SL = (size_t)nb * CHW_ * 2;
    const size_t ST = (size_t)nb * HW_ * 4;
    u16*   q    = (u16*)(ws);
    u16*   k    = (u16*)(ws + SL);
    u16*   v    = (u16*)(ws + 2 * SL);
    u16*   qNb  = (u16*)(ws + 3 * SL);
    u16*   kNb  = (u16*)(ws + 4 * SL);
    u16*   vT   = (u16*)(ws + 5 * SL);
    u16*   OtN  = (u16*)(ws + 6 * SL);
    float* maxH = (float*)(ws + 7 * SL);
    float* sumH = (float*)(ws + 7 * SL + ST);
    float* mF   = (float*)(ws + 7 * SL + 2 * ST);
    float* dn   = (float*)(ws + 7 * SL + 3 * ST);
    u16*   Wt   = (u16*)(ws + 7 * SL + 4 * ST);

    dim3 blk(256);
    prep_weights<<<dim3(9, 48), blk, 0, stream>>>(Wq, Wk, Wv, Wt);

    for (int p = 0; p < passes; p++) {
        const float* xb = x + (size_t)p * nb * CHW_;
        float* ob = out + (size_t)p * nb * CHW_;
        conv_mfma_kernel<<<dim3(H_, nb), blk, 0, stream>>>(xb, Wt, bq, bk, bv, q, k, v);
        nhwc_kernel<<<dim3(256, 2, nb), blk, 0, stream>>>(q, k, qNb, kNb);
        vt_kernel<<<dim3(4, C_, nb), blk, 0, stream>>>(v, vT);
        attn_kernel<0, true ><<<dim3(W_, 1, nb), blk, 0, stream>>>(qNb, kNb, vT, xb, gm, maxH, sumH, mF, dn, OtN, ob);
        attn_kernel<0, false><<<dim3(H_, 1, nb), blk, 0, stream>>>(qNb, kNb, v,  xb, gm, maxH, sumH, mF, dn, OtN, ob);
        attn_kernel<1, true ><<<dim3(W_, 1, nb), blk, 0, stream>>>(qNb, kNb, vT, xb, gm, maxH, sumH, mF, dn, OtN, ob);
        attn_kernel<1, false><<<dim3(H_, 1, nb), blk, 0, stream>>>(qNb, kNb, v,  xb, gm, maxH, sumH, mF, dn, OtN, ob);
    }
}

// Round 8
// 203.950 us; speedup vs baseline: 3.9599x; 1.1799x over previous
//
#include <hip/hip_runtime.h>
#include <hip/hip_bf16.h>

#define B_ 8
#define C_ 64
#define H_ 128
#define W_ 128
#define HW_  ((size_t)H_ * W_)          // 16384
#define CHW_ ((size_t)C_ * H_ * W_)     // 1048576

typedef unsigned short u16;
typedef unsigned int   u32;
typedef __attribute__((ext_vector_type(8))) short bf16x8;
typedef __attribute__((ext_vector_type(4))) float f32x4;

__device__ __forceinline__ float bf2f(u16 h) {
    union { u32 u; float f; } c; c.u = ((u32)h) << 16; return c.f;
}
__device__ __forceinline__ u16 f2bf(float f) {
    union { float f; u32 u; } c; c.f = f;
    u32 u = c.u;
    u32 r = (u + 0x7fffu + ((u >> 16) & 1u)) >> 16;
    return (u16)r;
}
__device__ __forceinline__ u32 pack2(float a, float b) {
    return (u32)f2bf(a) | ((u32)f2bf(b) << 16);
}
__device__ __forceinline__ float sanit(float x, float lo, float hi) {
    return fminf(fmaxf(x, lo), hi);   // NaN-killing clamp
}

// ---------------------------------------------------------------------------
// Weight prep: Wt[tap][cog(192)][ci(64)] bf16, cog = {q:0..63, k:64..127, v:128..191}
// ---------------------------------------------------------------------------
__global__ __launch_bounds__(256) void prep_weights(
    const float* __restrict__ Wq, const float* __restrict__ Wk,
    const float* __restrict__ Wv, u16* __restrict__ Wt)
{
    int tap = blockIdx.x;
    int cog = blockIdx.y * 4 + (threadIdx.x >> 6);
    int ci  = threadIdx.x & 63;
    int arr = cog >> 6, co = cog & 63;
    const float* src = arr == 0 ? Wq : (arr == 1 ? Wk : Wv);
    Wt[tap * 12288 + cog * 64 + ci] = f2bf(src[(co * 64 + ci) * 9 + tap]);
}

// ---------------------------------------------------------------------------
// Conv implicit-GEMM MFMA, single-stage. grid (H, nb), 4 waves.
// Stages all 3 halo rows to LDS once (1 barrier), 432 MFMAs/wave, then
// epilogue: qN,kN written NHWC via LDS transpose; v written NCHW direct.
// LDS: xI[3 dh][8 g][130 px][8 ch] bf16 = 49920 B, reused as T[2][128][72].
// ---------------------------------------------------------------------------
__global__ __launch_bounds__(256, 2) void conv_mfma_kernel(
    const float* __restrict__ x, const u16* __restrict__ Wt,
    const float* __restrict__ bq, const float* __restrict__ bk,
    const float* __restrict__ bv,
    u16* __restrict__ qN, u16* __restrict__ kN, u16* __restrict__ v)
{
    const int h    = blockIdx.x;
    const size_t boff = (size_t)blockIdx.y * CHW_;
    const int tid  = threadIdx.x;
    const int lane = tid & 63, wv = tid >> 6;
    const int ln15 = lane & 15, quad = lane >> 4;

    __shared__ __align__(16) u16 xI[24960];    // 49920 B

    // zero w-halos (pix slots 0 and 129) for all 3 dh rows
    if (tid < 48) {
        int dh = tid >> 4, g = (tid & 15) >> 1, p = (tid & 1) ? 129 : 0;
        *(uint4*)(xI + dh * 8320 + g * 1040 + p * 8) = (uint4){0, 0, 0, 0};
    }

    // stage 3 rows: 64 ch x 128 px fp32 -> bf16 channel-interleaved
#pragma unroll
    for (int it = 0; it < 12; it++) {
        int vid  = tid + it * 256;             // 0..3071
        int w4   = vid & 31;
        int rest = vid >> 5;                   // 0..95
        int dh   = rest >> 5;                  // 0..2
        int cp   = rest & 31;
        int c    = cp * 2;
        int h2   = h - 1 + dh;
        float4 f0 = {0.f, 0.f, 0.f, 0.f}, f1 = {0.f, 0.f, 0.f, 0.f};
        if (h2 >= 0 && h2 < H_) {
            const float* xrow = x + boff + (size_t)h2 * W_;
            f0 = *(const float4*)(xrow + (size_t)c * HW_ + w4 * 4);
            f1 = *(const float4*)(xrow + (size_t)(c + 1) * HW_ + w4 * 4);
        }
        float a0[4] = {f0.x, f0.y, f0.z, f0.w};
        float a1[4] = {f1.x, f1.y, f1.z, f1.w};
        int g = c >> 3, e = c & 7;
        u16* base = xI + dh * 8320 + g * 1040;
#pragma unroll
        for (int i = 0; i < 4; i++)
            *(u32*)(base + (w4 * 4 + i + 1) * 8 + e) = pack2(a0[i], a1[i]);
    }
    __syncthreads();

    f32x4 acc[3][8];
#pragma unroll
    for (int mt = 0; mt < 3; mt++)
#pragma unroll
        for (int nt = 0; nt < 8; nt++)
            acc[mt][nt] = (f32x4){0.f, 0.f, 0.f, 0.f};

#pragma unroll
    for (int dh = 0; dh < 3; dh++) {
        const u16* xrow = xI + dh * 8320;
#pragma unroll
        for (int dw = 0; dw < 3; dw++) {
            const u16* wt = Wt + (dh * 3 + dw) * 12288;
#pragma unroll
            for (int ks = 0; ks < 2; ks++) {
                bf16x8 af[3], bfr[8];
#pragma unroll
                for (int mt = 0; mt < 3; mt++)
                    af[mt] = *(const bf16x8*)(wt + (wv * 48 + mt * 16 + ln15) * 64 + ks * 32 + quad * 8);
#pragma unroll
                for (int nt = 0; nt < 8; nt++)
                    bfr[nt] = *(const bf16x8*)(xrow + ((quad + ks * 4) * 1040 + (nt * 16 + ln15 + dw) * 8));
#pragma unroll
                for (int mt = 0; mt < 3; mt++)
#pragma unroll
                    for (int nt = 0; nt < 8; nt++)
                        acc[mt][nt] = __builtin_amdgcn_mfma_f32_16x16x32_bf16(
                            af[mt], bfr[nt], acc[mt][nt], 0, 0, 0);
            }
        }
    }

    __syncthreads();                 // xI reads done; reuse as T
    u16* T = xI;                     // [arr(2)][128 px][72]
#pragma unroll
    for (int mt = 0; mt < 3; mt++) {
        int base = wv * 48 + mt * 16;
        int arr  = base >> 6;
        if (arr < 2) {               // q or k: to LDS transpose buffer
            const float* bias = arr == 0 ? bq : bk;
            int cb = (base & 63) + quad * 4;
#pragma unroll
            for (int r = 0; r < 4; r++) {
                float bb = bias[cb + r];
#pragma unroll
                for (int nt = 0; nt < 8; nt++)
                    T[arr * 9216 + (nt * 16 + ln15) * 72 + cb + r] = f2bf(acc[mt][nt][r] + bb);
            }
        } else {                     // v: NCHW direct
            int cb = (base & 63) + quad * 4;
#pragma unroll
            for (int r = 0; r < 4; r++) {
                float bb = bv[cb + r];
                u16* drow = v + boff + (size_t)(cb + r) * HW_ + (size_t)h * W_;
#pragma unroll
                for (int nt = 0; nt < 8; nt++)
                    drow[nt * 16 + ln15] = f2bf(acc[mt][nt][r] + bb);
            }
        }
    }
    __syncthreads();
    // qN,kN NHWC coalesced store: 2 arrays x 128 px x 64 c
#pragma unroll
    for (int it = 0; it < 8; it++) {
        int idx = tid + it * 256;              // 0..2047
        int arr = idx >> 10, rem = idx & 1023;
        int px = rem >> 3, c8 = (rem & 7) * 8;
        uint4 val = *(uint4*)(T + arr * 9216 + px * 72 + c8);
        u16* dst = (arr ? kN : qN) + boff + ((size_t)h * W_ + px) * 64 + c8;
        *(uint4*)dst = val;
    }
}

// ---------------------------------------------------------------------------
// vT: [c][h][w] -> [c][w][h] (64x64 tiles). grid (4, C, nb).
// ---------------------------------------------------------------------------
__global__ __launch_bounds__(256) void vt_kernel(
    const u16* __restrict__ v, u16* __restrict__ vT)
{
    __shared__ u16 Ts[64 * 72];
    const u16* src = v  + (size_t)blockIdx.z * CHW_ + (size_t)blockIdx.y * HW_;
    u16* dst       = vT + (size_t)blockIdx.z * CHW_ + (size_t)blockIdx.y * HW_;
    const int ti = blockIdx.x & 1, tj = blockIdx.x >> 1;
    const int r0 = ti * 64, c0 = tj * 64;
    const int tid = threadIdx.x;
    const int r = tid >> 2, cq = tid & 3;
#pragma unroll
    for (int i = 0; i < 2; i++) {
        uint4 u = *(const uint4*)(src + (size_t)(r0 + r) * 128 + c0 + cq * 16 + i * 8);
        *(uint4*)(Ts + r * 72 + cq * 16 + i * 8) = u;
    }
    __syncthreads();
    const int wr = tid >> 2, hq = tid & 3;
    union { u16 o[16]; uint4 v4[2]; } t;
#pragma unroll
    for (int j = 0; j < 16; j++) t.o[j] = Ts[(hq * 16 + j) * 72 + wr];
    *(uint4*)(dst + (size_t)(c0 + wr) * 128 + r0 + hq * 16)     = t.v4[0];
    *(uint4*)(dst + (size_t)(c0 + wr) * 128 + r0 + hq * 16 + 8) = t.v4[1];
}

// ---------------------------------------------------------------------------
// Column attention (flash pass 1). Block = (w, b). S = QK^T over h with diag
// mask; LOCAL softmax stats (m,Σ) -> maxH,sumH; unnormalized
// Ocol[t][c] = Σ_g e^{S-m} V -> fp32 NHWC.
// ---------------------------------------------------------------------------
__global__ __launch_bounds__(256, 3) void col_kernel(
    const u16* __restrict__ qN, const u16* __restrict__ kN,
    const u16* __restrict__ vT,
    float* __restrict__ maxH, float* __restrict__ sumH,
    float* __restrict__ Ocol)
{
    const size_t boff = (size_t)blockIdx.z * CHW_;
    const size_t soff = (size_t)blockIdx.z * HW_;
    qN += boff; kN += boff; vT += boff; Ocol += boff;
    maxH += soff; sumH += soff;

    const int s    = blockIdx.x;               // w
    const int tid  = threadIdx.x;
    const int lane = tid & 63, wv = tid >> 6;
    const int ln15 = lane & 15, quad = lane >> 4;

    __shared__ __align__(16) u16 smemU[18432]; // 36864 B
    u16* Qs = smemU;                           // [128 t][72]
    u16* Ks = smemU + 9216;

#pragma unroll
    for (int it = 0; it < 4; it++) {
        int idx = tid + it * 256;
        int t = idx >> 3, cg = (idx & 7) * 8;
        size_t off = (size_t)t * 8192 + (size_t)s * 64 + cg;
        *(uint4*)(Qs + t * 72 + cg) = *(const uint4*)(qN + off);
        *(uint4*)(Ks + t * 72 + cg) = *(const uint4*)(kN + off);
    }
    __syncthreads();

    f32x4 Sc[2][8];
#pragma unroll
    for (int mt = 0; mt < 2; mt++)
#pragma unroll
        for (int nt = 0; nt < 8; nt++)
            Sc[mt][nt] = (f32x4){0.f, 0.f, 0.f, 0.f};

#pragma unroll
    for (int ks = 0; ks < 2; ks++) {
        bf16x8 aq[2];
#pragma unroll
        for (int mt = 0; mt < 2; mt++)
            aq[mt] = *(const bf16x8*)(Qs + (wv * 32 + mt * 16 + ln15) * 72 + ks * 32 + quad * 8);
#pragma unroll
        for (int nt = 0; nt < 8; nt++) {
            bf16x8 bk_ = *(const bf16x8*)(Ks + (nt * 16 + ln15) * 72 + ks * 32 + quad * 8);
#pragma unroll
            for (int mt = 0; mt < 2; mt++)
                Sc[mt][nt] = __builtin_amdgcn_mfma_f32_16x16x32_bf16(aq[mt], bk_, Sc[mt][nt], 0, 0, 0);
        }
    }
    // diag mask t==g
#pragma unroll
    for (int mt = 0; mt < 2; mt++)
#pragma unroll
        for (int nt = 0; nt < 8; nt++)
#pragma unroll
            for (int r = 0; r < 4; r++) {
                int tt = wv * 32 + mt * 16 + quad * 4 + r;
                if (tt == nt * 16 + ln15) Sc[mt][nt][r] = -1e30f;
            }

    // local stats + unnormalized P
    float mloc[2][4];
#pragma unroll
    for (int mt = 0; mt < 2; mt++)
#pragma unroll
        for (int r = 0; r < 4; r++) {
            float m = Sc[mt][0][r];
#pragma unroll
            for (int nt = 1; nt < 8; nt++) m = fmaxf(m, Sc[mt][nt][r]);
            for (int o = 1; o < 16; o <<= 1) m = fmaxf(m, __shfl_xor(m, o));
            float ss = 0.f;
#pragma unroll
            for (int nt = 0; nt < 8; nt++) ss += __expf(Sc[mt][nt][r] - m);
            for (int o = 1; o < 16; o <<= 1) ss += __shfl_xor(ss, o);
            mloc[mt][r] = m;
            if (ln15 == 0) {
                int tt = wv * 32 + mt * 16 + quad * 4 + r;
                int pix = tt * W_ + s;
                maxH[pix] = m; sumH[pix] = ss;
            }
        }
    __syncthreads();
    u16* Ps = smemU;                           // [128 t][136]
#pragma unroll
    for (int mt = 0; mt < 2; mt++)
#pragma unroll
        for (int nt = 0; nt < 8; nt++)
#pragma unroll
            for (int r = 0; r < 4; r++)
                Ps[(wv * 32 + mt * 16 + quad * 4 + r) * 136 + nt * 16 + ln15] =
                    f2bf(__expf(Sc[mt][nt][r] - mloc[mt][r]));
    __syncthreads();

    f32x4 Oc[2][4];
#pragma unroll
    for (int mt = 0; mt < 2; mt++)
#pragma unroll
        for (int nt = 0; nt < 4; nt++)
            Oc[mt][nt] = (f32x4){0.f, 0.f, 0.f, 0.f};
#pragma unroll
    for (int kg = 0; kg < 4; kg++) {
        bf16x8 ap[2];
#pragma unroll
        for (int mt = 0; mt < 2; mt++)
            ap[mt] = *(const bf16x8*)(Ps + (wv * 32 + mt * 16 + ln15) * 136 + kg * 32 + quad * 8);
#pragma unroll
        for (int nt = 0; nt < 4; nt++) {
            bf16x8 bv_ = *(const bf16x8*)(vT + (size_t)(nt * 16 + ln15) * HW_ + (size_t)s * 128 + kg * 32 + quad * 8);
#pragma unroll
            for (int mt = 0; mt < 2; mt++)
                Oc[mt][nt] = __builtin_amdgcn_mfma_f32_16x16x32_bf16(ap[mt], bv_, Oc[mt][nt], 0, 0, 0);
        }
    }
    __syncthreads();
    float* Of = (float*)smemU;                 // [128 t][68]
#pragma unroll
    for (int mt = 0; mt < 2; mt++)
#pragma unroll
        for (int nt = 0; nt < 4; nt++)
#pragma unroll
            for (int r = 0; r < 4; r++)
                Of[(wv * 32 + mt * 16 + quad * 4 + r) * 68 + nt * 16 + ln15] = Oc[mt][nt][r];
    __syncthreads();
#pragma unroll
    for (int it = 0; it < 8; it++) {
        int idx = tid + it * 256;              // 0..2047
        int t = idx >> 4, c4 = (idx & 15) * 4;
        *(float4*)(Ocol + ((size_t)t * 128 + s) * 64 + c4) = *(float4*)(Of + t * 68 + c4);
    }
}

// ---------------------------------------------------------------------------
// Row attention (flash pass 2 + epilogue). Block = (h, b). S = QK^T over w
// (no mask); merge local stats with col stats -> (m, d); P normalized; PV;
// out = gamma * (PV + alpha*Ocol) + x,  alpha = e^{m_col - m} / d.
// ---------------------------------------------------------------------------
__global__ __launch_bounds__(256, 3) void row_kernel(
    const u16* __restrict__ qN, const u16* __restrict__ kN,
    const u16* __restrict__ v,
    const float* __restrict__ x, const float* __restrict__ gammap,
    const float* __restrict__ maxH, const float* __restrict__ sumH,
    const float* __restrict__ Ocol, float* __restrict__ out)
{
    const size_t boff = (size_t)blockIdx.z * CHW_;
    const size_t soff = (size_t)blockIdx.z * HW_;
    qN += boff; kN += boff; v += boff; Ocol += boff; x += boff; out += boff;
    maxH += soff; sumH += soff;

    const int s    = blockIdx.x;               // h
    const int tid  = threadIdx.x;
    const int lane = tid & 63, wv = tid >> 6;
    const int ln15 = lane & 15, quad = lane >> 4;

    __shared__ __align__(16) u16 smemU[18432]; // 36864 B
    u16* Qs = smemU;
    u16* Ks = smemU + 9216;

#pragma unroll
    for (int it = 0; it < 4; it++) {
        int idx = tid + it * 256;
        int t = idx >> 3, cg = (idx & 7) * 8;
        size_t off = (size_t)s * 8192 + (size_t)t * 64 + cg;
        *(uint4*)(Qs + t * 72 + cg) = *(const uint4*)(qN + off);
        *(uint4*)(Ks + t * 72 + cg) = *(const uint4*)(kN + off);
    }
    __syncthreads();

    f32x4 Sc[2][8];
#pragma unroll
    for (int mt = 0; mt < 2; mt++)
#pragma unroll
        for (int nt = 0; nt < 8; nt++)
            Sc[mt][nt] = (f32x4){0.f, 0.f, 0.f, 0.f};
#pragma unroll
    for (int ks = 0; ks < 2; ks++) {
        bf16x8 aq[2];
#pragma unroll
        for (int mt = 0; mt < 2; mt++)
            aq[mt] = *(const bf16x8*)(Qs + (wv * 32 + mt * 16 + ln15) * 72 + ks * 32 + quad * 8);
#pragma unroll
        for (int nt = 0; nt < 8; nt++) {
            bf16x8 bk_ = *(const bf16x8*)(Ks + (nt * 16 + ln15) * 72 + ks * 32 + quad * 8);
#pragma unroll
            for (int mt = 0; mt < 2; mt++)
                Sc[mt][nt] = __builtin_amdgcn_mfma_f32_16x16x32_bf16(aq[mt], bk_, Sc[mt][nt], 0, 0, 0);
        }
    }

    // local stats, merge with col stats
    float mr[2][4], rr[2][4], al[2][4];
#pragma unroll
    for (int mt = 0; mt < 2; mt++)
#pragma unroll
        for (int r = 0; r < 4; r++) {
            float m = Sc[mt][0][r];
#pragma unroll
            for (int nt = 1; nt < 8; nt++) m = fmaxf(m, Sc[mt][nt][r]);
            for (int o = 1; o < 16; o <<= 1) m = fmaxf(m, __shfl_xor(m, o));
            float ss = 0.f;
#pragma unroll
            for (int nt = 0; nt < 8; nt++) ss += __expf(Sc[mt][nt][r] - m);
            for (int o = 1; o < 16; o <<= 1) ss += __shfl_xor(ss, o);
            int tt  = wv * 32 + mt * 16 + quad * 4 + r;
            int pix = s * W_ + tt;
            float mc = sanit(maxH[pix], -3e38f, 3e38f);
            float sc = sanit(sumH[pix], 0.f, 3e38f);
            float mm = fmaxf(mc, m);
            float dd = sc * __expf(fminf(mc - mm, 0.f)) + ss * __expf(fminf(m - mm, 0.f));
            float rv = 1.0f / fmaxf(dd, 1e-30f);
            mr[mt][r] = mm; rr[mt][r] = rv;
            al[mt][r] = __expf(fminf(mc - mm, 0.f)) * rv;
        }
    __syncthreads();
    u16* Ps = smemU;                           // [128 t][136]
#pragma unroll
    for (int mt = 0; mt < 2; mt++)
#pragma unroll
        for (int nt = 0; nt < 8; nt++)
#pragma unroll
            for (int r = 0; r < 4; r++)
                Ps[(wv * 32 + mt * 16 + quad * 4 + r) * 136 + nt * 16 + ln15] =
                    f2bf(__expf(fminf(Sc[mt][nt][r] - mr[mt][r], 0.f)) * rr[mt][r]);
    __syncthreads();

    f32x4 Oc[2][4];
#pragma unroll
    for (int mt = 0; mt < 2; mt++)
#pragma unroll
        for (int nt = 0; nt < 4; nt++)
            Oc[mt][nt] = (f32x4){0.f, 0.f, 0.f, 0.f};
#pragma unroll
    for (int kg = 0; kg < 4; kg++) {
        bf16x8 ap[2];
#pragma unroll
        for (int mt = 0; mt < 2; mt++)
            ap[mt] = *(const bf16x8*)(Ps + (wv * 32 + mt * 16 + ln15) * 136 + kg * 32 + quad * 8);
#pragma unroll
        for (int nt = 0; nt < 4; nt++) {
            bf16x8 bv_ = *(const bf16x8*)(v + (size_t)(nt * 16 + ln15) * HW_ + (size_t)s * 128 + kg * 32 + quad * 8);
#pragma unroll
            for (int mt = 0; mt < 2; mt++)
                Oc[mt][nt] = __builtin_amdgcn_mfma_f32_16x16x32_bf16(ap[mt], bv_, Oc[mt][nt], 0, 0, 0);
        }
    }
    __syncthreads();

    const float gmm = gammap[0];
    float* Of = (float*)smemU;                 // [64 c][132 w]
#pragma unroll
    for (int mt = 0; mt < 2; mt++)
#pragma unroll
        for (int nt = 0; nt < 4; nt++) {
            float fv[4];
            int c = nt * 16 + ln15;
#pragma unroll
            for (int r = 0; r < 4; r++) {
                int tt = wv * 32 + mt * 16 + quad * 4 + r;
                float oc = Ocol[((size_t)s * 128 + tt) * 64 + c];
                fv[r] = gmm * (Oc[mt][nt][r] + al[mt][r] * oc);
            }
            int w0 = wv * 32 + mt * 16 + quad * 4;
            *(float4*)(Of + c * 132 + w0) = make_float4(fv[0], fv[1], fv[2], fv[3]);
        }
    __syncthreads();
    int c = tid >> 2, w0 = (tid & 3) * 32;
#pragma unroll
    for (int i = 0; i < 8; i++) {
        int w = w0 + i * 4;
        float4 xo = *(const float4*)(x + (size_t)c * HW_ + (size_t)s * 128 + w);
        float4 of = *(const float4*)(Of + c * 132 + w);
        *(float4*)(out + (size_t)c * HW_ + (size_t)s * 128 + w) =
            make_float4(of.x + xo.x, of.y + xo.y, of.z + xo.z, of.w + xo.w);
    }
}

// ---------------------------------------------------------------------------
// ws: qN|kN|v|vT (bf16, nb*2MB each) + Ocol (fp32, nb*4MB) + maxH,sumH
// (nb*64KB each) + Wt 216KB. nb=8: 97.2MB (< proven 114MB). Fallback 2-pass.
// ---------------------------------------------------------------------------
extern "C" void kernel_launch(void* const* d_in, const int* in_sizes, int n_in,
                              void* d_out, int out_size, void* d_ws, size_t ws_size,
                              hipStream_t stream)
{
    const float* x  = (const float*)d_in[0];
    const float* Wq = (const float*)d_in[1];
    const float* bq = (const float*)d_in[2];
    const float* Wk = (const float*)d_in[3];
    const float* bk = (const float*)d_in[4];
    const float* Wv = (const float*)d_in[5];
    const float* bv = (const float*)d_in[6];
    const float* gm = (const float*)d_in[7];
    float* out = (float*)d_out;

    char* ws = (char*)d_ws;
    const size_t need1 = 4 * (size_t)B_ * CHW_ * 2 + (size_t)B_ * CHW_ * 4
                       + 2 * (size_t)B_ * HW_ * 4 + 221184;
    int passes = (ws_size >= need1) ? 1 : 2;
    int nb = B_ / passes;

    const size_t SL = (size_t)nb * CHW_ * 2;
    const size_t OC = (size_t)nb * CHW_ * 4;
    const size_t ST = (size_t)nb * HW_ * 4;
    u16*   qNb  = (u16*)(ws);
    u16*   kNb  = (u16*)(ws + SL);
    u16*   v    = (u16*)(ws + 2 * SL);
    u16*   vT   = (u16*)(ws + 3 * SL);
    float* Ocol = (float*)(ws + 4 * SL);
    float* maxH = (float*)(ws + 4 * SL + OC);
    float* sumH = (float*)(ws + 4 * SL + OC + ST);
    u16*   Wt   = (u16*)(ws + 4 * SL + OC + 2 * ST);

    dim3 blk(256);
    prep_weights<<<dim3(9, 48), blk, 0, stream>>>(Wq, Wk, Wv, Wt);

    for (int p = 0; p < passes; p++) {
        const float* xb = x + (size_t)p * nb * CHW_;
        float* ob = out + (size_t)p * nb * CHW_;
        conv_mfma_kernel<<<dim3(H_, nb), blk, 0, stream>>>(xb, Wt, bq, bk, bv, qNb, kNb, v);
        vt_kernel<<<dim3(4, C_, nb), blk, 0, stream>>>(v, vT);
        col_kernel<<<dim3(W_, 1, nb), blk, 0, stream>>>(qNb, kNb, vT, maxH, sumH, Ocol);
        row_kernel<<<dim3(H_, 1, nb), blk, 0, stream>>>(qNb, kNb, v, xb, gm, maxH, sumH, Ocol, ob);
    }
}